// Round 3
// baseline (1257.416 us; speedup 1.0000x reference)
//
#include <hip/hip_runtime.h>
#include <hip/hip_bf16.h>

typedef __hip_bfloat16 bf16;

__device__ __forceinline__ float b2f(bf16 v) { return __bfloat162float(v); }
__device__ __forceinline__ bf16 f2b(float v) { return __float2bfloat16(v); }

// Dual-dtype load: input edge tensors may be fp32 or bf16, decided at runtime.
__device__ __forceinline__ float ldv(const void* p, size_t i, bool f32) {
    return f32 ? ((const float*)p)[i] : b2f(((const bf16*)p)[i]);
}

// ---------------- K-1: dtype detector ----------------
// If the buffer holds fp32, even-indexed ushorts are low-mantissa garbage:
// ~64/8192 hit exponent-field all-ones/all-zeros. True bf16 N(0,1): 0 hits.
__global__ void k_detect(const void* x, int* flag) {
    __shared__ int cnt;
    if (threadIdx.x == 0) cnt = 0;
    __syncthreads();
    const unsigned short* us = (const unsigned short*)x;
    int local = 0;
    for (int i = threadIdx.x; i < 8192; i += 256) {
        unsigned e = us[2 * i] & 0x7F80u;
        if (e == 0x7F80u || e == 0u) local++;
    }
    atomicAdd(&cnt, local);
    __syncthreads();
    if (threadIdx.x == 0) flag[0] = (cnt >= 8) ? 1 : 0;
}

// ---------------- K0: weight prep ----------------
__global__ void k_prep(const void* gw, const void* gb, const void* tw, const void* tb,
                       const void* pw, const void* pb, const void* ww, const void* wb,
                       const void* cw, const void* bng, const void* bnb,
                       const void* bnm, const void* bnv, const int* flag,
                       float* __restrict__ wth, float* __restrict__ bth,
                       float* __restrict__ wgp, float* __restrict__ bgp,
                       float* __restrict__ wwT, float* __restrict__ wbf,
                       float* __restrict__ wfold, float* __restrict__ bfold)
{
    bool f32 = flag[0] != 0;
    int gid = blockIdx.x * 256 + threadIdx.x;
    int stride = gridDim.x * 256;
    // wth[k][32]: theta weights, k = input channel 0..63
    for (int e = gid; e < 64 * 32; e += stride) {
        int k = e / 32, c = e % 32;
        wth[e] = ldv(tw, (size_t)c * 64 + k, f32);
    }
    for (int e = gid; e < 32; e += stride) bth[e] = ldv(tb, e, f32);
    // wgp[k][64]: cols [g 0..31 | phi 32..63]
    for (int e = gid; e < 64 * 64; e += stride) {
        int k = e / 64, cc = e % 64;
        wgp[e] = (cc < 32) ? ldv(gw, (size_t)cc * 64 + k, f32)
                           : ldv(pw, (size_t)(cc - 32) * 64 + k, f32);
    }
    for (int e = gid; e < 64; e += stride)
        bgp[e] = (e < 32) ? ldv(gb, e, f32) : ldv(pb, e - 32, f32);
    // wwT[c][o]
    for (int e = gid; e < 32 * 64; e += stride) {
        int c = e / 64, o = e % 64;
        wwT[e] = ldv(ww, (size_t)o * 32 + c, f32);
    }
    for (int e = gid; e < 64; e += stride) wbf[e] = ldv(wb, e, f32);
    // wfold[c][tap][o] = cw[o][c][tap] * inv[o]
    for (int e = gid; e < 64 * 9 * 32; e += stride) {
        int c = e / 288, r = e % 288, tap = r / 32, o = r % 32;
        float inv = ldv(bng, o, f32) * rsqrtf(ldv(bnv, o, f32) + 1e-5f);
        wfold[e] = ldv(cw, ((size_t)o * 64 + c) * 9 + tap, f32) * inv;
    }
    for (int e = gid; e < 32; e += stride) {
        float inv = ldv(bng, e, f32) * rsqrtf(ldv(bnv, e, f32) + 1e-5f);
        bfold[e] = ldv(bnb, e, f32) - ldv(bnm, e, f32) * inv;
    }
}

// ---------------- K1: g/phi 1x1 conv, thread per pixel ----------------
__global__ void k_gp(const void* f1, const void* f2, const int* flag,
                     const float* __restrict__ wgp, const float* __restrict__ bgp,
                     bf16* __restrict__ gfull, bf16* __restrict__ pfull, int N)
{
    bool f32 = flag[0] != 0;
    int gid = blockIdx.x * 256 + threadIdx.x;
    int b = gid / N;
    int ii = gid - b * N;
    float acc[64];
#pragma unroll
    for (int c = 0; c < 64; c++) acc[c] = bgp[c];
    size_t base = (size_t)b * 32 * N + ii;
    for (int k = 0; k < 32; k++) {
        float xv = ldv(f1, base + (size_t)k * N, f32);
        const float* w = wgp + k * 64;
#pragma unroll
        for (int c = 0; c < 64; c++) acc[c] += xv * w[c];
    }
    for (int k = 0; k < 32; k++) {
        float xv = ldv(f2, base + (size_t)k * N, f32);
        const float* w = wgp + (k + 32) * 64;
#pragma unroll
        for (int c = 0; c < 64; c++) acc[c] += xv * w[c];
    }
    bf16* gp = gfull + (size_t)gid * 32;
    bf16* pp = pfull + (size_t)gid * 32;
#pragma unroll
    for (int c = 0; c < 32; c++) gp[c] = f2b(acc[c]);
#pragma unroll
    for (int c = 0; c < 32; c++) pp[c] = f2b(acc[32 + c]);
}

// ---------------- K2: max pool (s x s) ----------------
__global__ void k_pool(const bf16* __restrict__ gfull, const bf16* __restrict__ pfull,
                       bf16* __restrict__ gp, bf16* __restrict__ pp,
                       int n, int W, int s, int wp, int total)
{
    int gid = blockIdx.x * 256 + threadIdx.x;
    if (gid >= total) return;
    int c = gid & 31;
    int j = (gid >> 5) % n;
    int b = gid / (32 * n);
    int py = j / wp, px = j % wp;
    const int N = W * W;
    float mg = -INFINITY, mp = -INFINITY;
    for (int dy = 0; dy < s; dy++)
        for (int dx = 0; dx < s; dx++) {
            int idx = (py * s + dy) * W + px * s + dx;
            size_t base = ((size_t)b * N + idx) * 32 + c;
            mg = fmaxf(mg, b2f(gfull[base]));
            mp = fmaxf(mp, b2f(pfull[base]));
        }
    size_t o = ((size_t)b * n + j) * 32 + c;
    gp[o] = f2b(mg);
    pp[o] = f2b(mp);
}

// ---------------- K3: fused theta-conv + online-softmax attention + W-conv + residual ----------------
// Block = 64 pixels. 4 waves each own a j-chunk; theta recomputed per wave (1.3% FLOPs).
// Epilogue: y (LDS) -> z = wwT*y + b + x, planar bf16.
__launch_bounds__(256)
__global__ void k_attn_fused(const void* f1, const void* f2, const int* flag,
                             const float* __restrict__ wth, const float* __restrict__ bth,
                             const float* __restrict__ wwT, const float* __restrict__ wbf,
                             const bf16* __restrict__ phi, const bf16* __restrict__ g,
                             bf16* __restrict__ z, int N, int n)
{
    bool f32 = flag[0] != 0;
    __shared__ float sm[4][64];
    __shared__ float sl[4][64];
    __shared__ float sy[4][64 * 33];   // stride 33: conflict-free column reads
    int tid = threadIdx.x;
    int lane = tid & 63;
    int wv = tid >> 6;
    int row0 = blockIdx.x * 64;        // N % 64 == 0 -> whole block in one batch image
    int b = row0 / N;
    int ii0 = row0 - b * N;
    int ii = ii0 + lane;
    int bn = b * n;

    // theta on the fly for this lane's pixel
    float t[32];
#pragma unroll
    for (int c = 0; c < 32; c++) t[c] = bth[c];
    size_t base = (size_t)b * 32 * N + ii;
    for (int k = 0; k < 32; k++) {
        float xv = ldv(f1, base + (size_t)k * N, f32);
        const float* w = wth + k * 32;
#pragma unroll
        for (int c = 0; c < 32; c++) t[c] += xv * w[c];
    }
    for (int k = 0; k < 32; k++) {
        float xv = ldv(f2, base + (size_t)k * N, f32);
        const float* w = wth + (k + 32) * 32;
#pragma unroll
        for (int c = 0; c < 32; c++) t[c] += xv * w[c];
    }

    int js = (n * wv) >> 2;
    int je = (n * (wv + 1)) >> 2;
    float m = -INFINITY, l = 0.f;
    float acc[32];
#pragma unroll
    for (int c = 0; c < 32; c++) acc[c] = 0.f;

    for (int j = js; j < je; j++) {
        const bf16* ph = phi + ((size_t)(bn + j)) * 32;
        float f = 0.f;
#pragma unroll
        for (int c = 0; c < 32; c++) f += t[c] * b2f(ph[c]);
        if (f > m) {
            float sc = __expf(m - f);
            l *= sc;
#pragma unroll
            for (int c = 0; c < 32; c++) acc[c] *= sc;
            m = f;
        }
        float p = __expf(f - m);
        l += p;
        const bf16* gr = g + ((size_t)(bn + j)) * 32;
#pragma unroll
        for (int c = 0; c < 32; c++) acc[c] += p * b2f(gr[c]);
    }

    sm[wv][lane] = m;
    sl[wv][lane] = l;
#pragma unroll
    for (int c = 0; c < 32; c++) sy[wv][lane * 33 + c] = acc[c];
    __syncthreads();

    // merge 4 partials; normalized y written in-place over sy[0]
    {
        int r = tid >> 2, q = tid & 3;
        float M = fmaxf(fmaxf(sm[0][r], sm[1][r]), fmaxf(sm[2][r], sm[3][r]));
        float e0 = __expf(sm[0][r] - M), e1 = __expf(sm[1][r] - M);
        float e2 = __expf(sm[2][r] - M), e3 = __expf(sm[3][r] - M);
        float L = e0 * sl[0][r] + e1 * sl[1][r] + e2 * sl[2][r] + e3 * sl[3][r];
        float invL = 1.f / L;
#pragma unroll
        for (int cc = 0; cc < 8; cc++) {
            int c = q * 8 + cc;
            int idx = r * 33 + c;
            float v = e0 * sy[0][idx] + e1 * sy[1][idx] + e2 * sy[2][idx] + e3 * sy[3][idx];
            sy[0][idx] = v * invL;   // each slot read+written only by this thread
        }
    }
    __syncthreads();

    // epilogue: z[o][pixel] = wwT*y + wbf + x ; wave wv owns o in [16wv, 16wv+16)
    float yrow[32];
#pragma unroll
    for (int c = 0; c < 32; c++) yrow[c] = sy[0][lane * 33 + c];
    const void* fx = (wv < 2) ? f1 : f2;
    int o0 = wv * 16;
    for (int oo = 0; oo < 16; oo++) {
        int o = o0 + oo;
        int op = (o < 32) ? o : o - 32;
        float a = wbf[o];
        const float* w = wwT + o;       // wwT[c*64+o], uniform scalar loads
#pragma unroll
        for (int c = 0; c < 32; c++) a += yrow[c] * w[c * 64];
        a += ldv(fx, (size_t)(b * 32 + op) * N + ii, f32);
        z[((size_t)(b * 64 + o)) * N + ii] = f2b(a);
    }
}

// ---------------- K5: 3x3 conv (64->32) + folded BN ----------------
__launch_bounds__(256)
__global__ void k_conv3(const bf16* __restrict__ z, const float* __restrict__ wfold,
                        const float* __restrict__ bfold, void* out, size_t outOff,
                        const int* flag, int H, int tX)
{
    bool f32 = flag[0] != 0;
    __shared__ float zs[16 * 324];   // 16 channels x 18x18 halo
    const int W = H, Npix = H * W;
    int tid = threadIdx.x;
    int tilesPerImg = tX * tX;
    int b = blockIdx.x / tilesPerImg;
    int t = blockIdx.x % tilesPerImg;
    int ty = t / tX, tx = t % tX;
    int ly = tid >> 4, lx = tid & 15;
    int oy = ty * 16 + ly, ox = tx * 16 + lx;
    bool act = (oy < H) && (ox < W);
    float acc[32];
#pragma unroll
    for (int o = 0; o < 32; o++) acc[o] = 0.f;

    for (int cc = 0; cc < 4; cc++) {
        __syncthreads();
        for (int e = tid; e < 16 * 324; e += 256) {
            int c = e / 324, r = e % 324, yy = r / 18, xx = r % 18;
            int gy = ty * 16 - 1 + yy, gx = tx * 16 - 1 + xx;
            float v = 0.f;
            if (gy >= 0 && gy < H && gx >= 0 && gx < W)
                v = b2f(z[((size_t)(b * 64 + cc * 16 + c)) * Npix + gy * W + gx]);
            zs[e] = v;
        }
        __syncthreads();
        if (act) {
            for (int c = 0; c < 16; c++) {
#pragma unroll
                for (int dy = 0; dy < 3; dy++)
#pragma unroll
                    for (int dx = 0; dx < 3; dx++) {
                        float zv = zs[c * 324 + (ly + dy) * 18 + (lx + dx)];
                        const float* w = wfold + ((size_t)(cc * 16 + c) * 9 + dy * 3 + dx) * 32;
#pragma unroll
                        for (int o = 0; o < 32; o++) acc[o] += zv * w[o];
                    }
            }
        }
    }
    if (act) {
        size_t ob = outOff + (size_t)b * 32 * Npix + (size_t)oy * W + ox;
        if (f32) {
            float* op = (float*)out;
#pragma unroll
            for (int o = 0; o < 32; o++) op[ob + (size_t)o * Npix] = acc[o] + bfold[o];
        } else {
            bf16* op = (bf16*)out;
#pragma unroll
            for (int o = 0; o < 32; o++) op[ob + (size_t)o * Npix] = f2b(acc[o] + bfold[o]);
        }
    }
}

extern "C" void kernel_launch(void* const* d_in, const int* in_sizes, int n_in,
                              void* d_out, int out_size, void* d_ws, size_t ws_size,
                              hipStream_t stream)
{
    const int B = 4;
    const int Hs[3] = {96, 48, 24};
    const int ss[3] = {2, 4, 8};
    const size_t outOff[3] = {0, 1179648, 1474560};

    int* flag = (int*)d_ws;
    float* wsf = (float*)d_ws + 16;
    // fp32 weight region (26816 floats)
    size_t o_wth = 0, o_bth = o_wth + 2048, o_wgp = o_bth + 32, o_bgp = o_wgp + 4096;
    size_t o_wwT = o_bgp + 64, o_wbf = o_wwT + 2048, o_wfold = o_wbf + 64;
    size_t o_bfold = o_wfold + 18432;                   // end = 26816
    // bf16 region: [gfull | pfull | gp | pp]; z (BN*64) overlays gfull+pfull
    bf16* bb = (bf16*)(wsf + 26816);
    const size_t BN1 = (size_t)B * 9216, Bn1 = (size_t)B * 2304;
    size_t o_g = 0;
    size_t o_p = o_g + BN1 * 32;
    size_t o_gp = o_p + BN1 * 32;
    size_t o_pp = o_gp + Bn1 * 32;
    // total ws: ~107KB + 5.9MB bf16 = 6.0 MB

    k_detect<<<1, 256, 0, stream>>>(d_in[0], flag);

    for (int lv = 0; lv < 3; lv++) {
        int H = Hs[lv], W = H, N = H * W, s = ss[lv];
        int wp = W / s, n = wp * wp;
        const void* f1 = d_in[2 * lv];
        const void* f2 = d_in[2 * lv + 1];
        const int wb0 = 6 + 13 * lv;
        k_prep<<<32, 256, 0, stream>>>(d_in[wb0 + 0], d_in[wb0 + 1], d_in[wb0 + 2],
                                       d_in[wb0 + 3], d_in[wb0 + 4], d_in[wb0 + 5],
                                       d_in[wb0 + 6], d_in[wb0 + 7], d_in[wb0 + 8],
                                       d_in[wb0 + 9], d_in[wb0 + 10], d_in[wb0 + 11],
                                       d_in[wb0 + 12], flag,
                                       wsf + o_wth, wsf + o_bth, wsf + o_wgp, wsf + o_bgp,
                                       wsf + o_wwT, wsf + o_wbf, wsf + o_wfold, wsf + o_bfold);
        int BN = B * N;
        k_gp<<<BN / 256, 256, 0, stream>>>(f1, f2, flag, wsf + o_wgp, wsf + o_bgp,
                                           bb + o_g, bb + o_p, N);
        int tot = B * n * 32;
        k_pool<<<(tot + 255) / 256, 256, 0, stream>>>(bb + o_g, bb + o_p,
                                                      bb + o_gp, bb + o_pp,
                                                      n, W, s, wp, tot);
        k_attn_fused<<<BN / 64, 256, 0, stream>>>(f1, f2, flag,
                                                  wsf + o_wth, wsf + o_bth,
                                                  wsf + o_wwT, wsf + o_wbf,
                                                  bb + o_pp, bb + o_gp,
                                                  bb + o_g, N, n);   // z overlays g/p
        int tX = (H + 15) / 16;
        k_conv3<<<B * tX * tX, 256, 0, stream>>>(bb + o_g, wsf + o_wfold, wsf + o_bfold,
                                                 d_out, outOff[lv], flag, H, tX);
    }
}